// Round 3
// baseline (132.820 us; speedup 1.0000x reference)
//
#include <hip/hip_runtime.h>
#include <math.h>

namespace {
constexpr int kB  = 16;
constexpr int kNV = 6890;
constexpr int kNF = 13776;
constexpr int kTF = 2 * kNF;              // 27552 triangles per person-pair
constexpr int kP  = kB / 2;               // 8 pairs
constexpr int kC  = 65536;
constexpr int kPenBlocks   = kP * (kC / 256);        // 2048
constexpr int kBuildChunks = (kTF + 255) / 256;      // 108
constexpr int kBuildBlocks = kP * kBuildChunks;      // 864
}
#define SIGMA_F 1e-4f
#define EPS_F   1e-9f
#define THRESH_F 2000.0f
#define WEIGHT_F 0.1f

// ws layout: [0..31] sums[8] floats, [64] counter (unsigned), [256..] cones, then verts64.
// cones:   per triangle 2 x float4 = {cx,cy,cz,inv_rad}, {nx,ny,nz,0}   (32 B, 1 line)
// verts64: per triangle 4 x float4 = {v0,v1,v2,pad}                     (64 B, 1 line)

// Kernel A: translate vertices, precompute cone frame; zero sums+counter.
// blk&7 = pair -> same XCD as pen's readers (round-robin block->XCD dispatch).
__global__ void __launch_bounds__(256)
build_kernel(const float* __restrict__ verts,
             const float* __restrict__ trans,
             const int*   __restrict__ faces,
             float* __restrict__ cones,
             float* __restrict__ tv,
             float* __restrict__ sums,
             unsigned* __restrict__ counter) {
    if (blockIdx.x == 0 && threadIdx.x <= kP) {
        if (threadIdx.x < kP) sums[threadIdx.x] = 0.0f;
        else *counter = 0u;
    }
    int blk = blockIdx.x;
    int p = blk & 7;
    int t = (blk >> 3) * 256 + threadIdx.x;
    if (t >= kTF) return;
    int half = (t >= kNF) ? 1 : 0;
    int b = 2 * p + half;
    int f = t - half * kNF;
    float tx = trans[3 * b + 0];
    float ty = trans[3 * b + 1];
    float tz = trans[3 * b + 2];
    float3 v[3];
    int g = p * kTF + t;
    float4* vdst = (float4*)(tv + (size_t)g * 16);
#pragma unroll
    for (int k = 0; k < 3; ++k) {
        int vi = faces[3 * f + k];
        const float* vp = verts + ((size_t)b * kNV + vi) * 3;
        v[k] = make_float3(vp[0] + tx, vp[1] + ty, vp[2] + tz);
        float4 o; o.x = v[k].x; o.y = v[k].y; o.z = v[k].z; o.w = 0.0f;
        vdst[k] = o;
    }
    // receiver cone frame (reference order of ops)
    float e1x = v[1].x - v[0].x, e1y = v[1].y - v[0].y, e1z = v[1].z - v[0].z;
    float e2x = v[2].x - v[0].x, e2y = v[2].y - v[0].y, e2z = v[2].z - v[0].z;
    float nx = e1y * e2z - e1z * e2y;
    float ny = e1z * e2x - e1x * e2z;
    float nz = e1x * e2y - e1y * e2x;
    float nn = sqrtf(nx * nx + ny * ny + nz * nz) + EPS_F;
    nx /= nn; ny /= nn; nz /= nn;
    float cx = (v[0].x + v[1].x + v[2].x) / 3.0f;
    float cy = (v[0].y + v[1].y + v[2].y) / 3.0f;
    float cz = (v[0].z + v[1].z + v[2].z) / 3.0f;
    float r2 = 0.0f;
#pragma unroll
    for (int k = 0; k < 3; ++k) {
        float dx = v[k].x - cx, dy = v[k].y - cy, dz = v[k].z - cz;
        r2 = fmaxf(r2, dx * dx + dy * dy + dz * dz);
    }
    float inv_rad = 1.0f / (sqrtf(r2) + EPS_F);
    float4* cdst = (float4*)(cones + (size_t)g * 8);
    float4 c0; c0.x = cx; c0.y = cy; c0.z = cz; c0.w = inv_rad;
    float4 c1; c1.x = nx; c1.y = ny; c1.z = nz; c1.w = 0.0f;
    cdst[0] = c0;
    cdst[1] = c1;
}

// Kernel B: one thread per collision; block reduce; last-block-ticket finalize.
__global__ void __launch_bounds__(256)
pen_kernel(const int* __restrict__ coll,
           const float* __restrict__ cones,
           const float* __restrict__ tv,
           float* __restrict__ sums,
           unsigned* __restrict__ counter,
           float* __restrict__ out) {
    int blk = blockIdx.x;
    int p = blk & 7;                         // XCD-pinned pair
    int i = (blk >> 3) * 256 + threadIdx.x;  // [0, 65536) exactly
    int2 idx = ((const int2*)coll)[p * kC + i];
    float local = 0.0f;
    if (idx.x != idx.y) {
        int rbase = p * kTF;
        const float4* cb = (const float4*)cones + (size_t)(rbase + idx.y) * 2;
        float4 c0 = cb[0];                   // centroid.xyz, 1/(radius+eps)
        float4 c1 = cb[1];                   // unit normal.xyz
        const float4* vb = (const float4*)tv + (size_t)(rbase + idx.x) * 4;
        float4 w0 = vb[0];
        float4 w1 = vb[1];
        float4 w2 = vb[2];
        float acc = 0.0f;
        float4 iv[3] = {w0, w1, w2};
#pragma unroll
        for (int k = 0; k < 3; ++k) {
            float dx = iv[k].x - c0.x, dy = iv[k].y - c0.y, dz = iv[k].z - c0.z;
            float d = dx * c1.x + dy * c1.y + dz * c1.z;
            float px = dx - d * c1.x, py = dy - d * c1.y, pz = dz - d * c1.z;
            float radial = sqrtf(px * px + py * py + pz * pz);
            float fa = fmaxf(-d / SIGMA_F, 0.0f);
            float fb = fmaxf(1.0f - radial * c0.w, 0.0f);
            float fd = fa * fb;
            acc += fd * fd;
        }
        local = acc;
    }
    // wave(64) reduce -> block reduce -> 1 atomic per block
#pragma unroll
    for (int off = 32; off > 0; off >>= 1)
        local += __shfl_down(local, off, 64);
    __shared__ float red[4];
    __shared__ unsigned is_last;
    int lane = threadIdx.x & 63;
    int wid  = threadIdx.x >> 6;
    if (lane == 0) red[wid] = local;
    __syncthreads();
    if (threadIdx.x == 0) {
        float s = red[0] + red[1] + red[2] + red[3];
        atomicAdd(&sums[p], s);
        __threadfence();
        unsigned t = atomicAdd(counter, 1u);
        is_last = (t == (unsigned)(kPenBlocks - 1)) ? 1u : 0u;
    }
    __syncthreads();
    if (is_last && threadIdx.x == 0) {
        __threadfence();
        float cnt = 0.0f, vals = 0.0f;
#pragma unroll
        for (int q = 0; q < kP; ++q) {
            float pen = atomicAdd(&sums[q], 0.0f);   // coherent read
            float keep = (pen < THRESH_F) ? 1.0f : 0.0f;
            cnt += keep;
            float s = 1.0f / (1.0f + expf(-pen / THRESH_F));
            vals += (s - 0.5f) * keep;
        }
        float loss = (cnt > 0.0f) ? (vals / fmaxf(cnt, 1.0f)) : 0.0f;
        out[0] = loss * WEIGHT_F;
    }
}

// ---------- fallback path (ws too small; not expected to run) ----------
__global__ void init_sums_kernel(float* __restrict__ sums) {
    int t = threadIdx.x;
    if (t < kP) sums[t] = 0.0f;
}

__global__ void __launch_bounds__(256)
pen_kernel_direct(const int* __restrict__ coll,
                  const float* __restrict__ verts,
                  const float* __restrict__ trans,
                  const int* __restrict__ faces,
                  float* __restrict__ sums) {
    int p = blockIdx.y;
    int i = blockIdx.x * blockDim.x + threadIdx.x;
    float local = 0.0f;
    if (i < kC) {
        int2 idx = ((const int2*)coll)[(size_t)p * kC + i];
        if (idx.x != idx.y) {
            float3 rv[3], iv[3];
#pragma unroll
            for (int s = 0; s < 2; ++s) {
                int t = s ? idx.x : idx.y;
                int half = (t >= kNF) ? 1 : 0;
                int b = 2 * p + half;
                int f = t - half * kNF;
                float tx = trans[3 * b + 0], ty = trans[3 * b + 1], tz = trans[3 * b + 2];
#pragma unroll
                for (int k = 0; k < 3; ++k) {
                    int vi = faces[3 * f + k];
                    const float* vp = verts + ((size_t)b * kNV + vi) * 3;
                    float3 vv = make_float3(vp[0] + tx, vp[1] + ty, vp[2] + tz);
                    if (s) iv[k] = vv; else rv[k] = vv;
                }
            }
            float e1x = rv[1].x - rv[0].x, e1y = rv[1].y - rv[0].y, e1z = rv[1].z - rv[0].z;
            float e2x = rv[2].x - rv[0].x, e2y = rv[2].y - rv[0].y, e2z = rv[2].z - rv[0].z;
            float nx = e1y * e2z - e1z * e2y;
            float ny = e1z * e2x - e1x * e2z;
            float nz = e1x * e2y - e1y * e2x;
            float nn = sqrtf(nx * nx + ny * ny + nz * nz) + EPS_F;
            nx /= nn; ny /= nn; nz /= nn;
            float cx = (rv[0].x + rv[1].x + rv[2].x) / 3.0f;
            float cy = (rv[0].y + rv[1].y + rv[2].y) / 3.0f;
            float cz = (rv[0].z + rv[1].z + rv[2].z) / 3.0f;
            float r2 = 0.0f;
#pragma unroll
            for (int k = 0; k < 3; ++k) {
                float dx = rv[k].x - cx, dy = rv[k].y - cy, dz = rv[k].z - cz;
                r2 = fmaxf(r2, dx * dx + dy * dy + dz * dz);
            }
            float inv_rad = sqrtf(r2) + EPS_F;
            float acc = 0.0f;
#pragma unroll
            for (int k = 0; k < 3; ++k) {
                float dx = iv[k].x - cx, dy = iv[k].y - cy, dz = iv[k].z - cz;
                float d = dx * nx + dy * ny + dz * nz;
                float px = dx - d * nx, py = dy - d * ny, pz = dz - d * nz;
                float radial = sqrtf(px * px + py * py + pz * pz);
                float fa = fmaxf(-d / SIGMA_F, 0.0f);
                float fb = fmaxf(1.0f - radial / inv_rad, 0.0f);
                float fd = fa * fb;
                acc += fd * fd;
            }
            local = acc;
        }
    }
#pragma unroll
    for (int off = 32; off > 0; off >>= 1)
        local += __shfl_down(local, off, 64);
    __shared__ float red[4];
    int lane = threadIdx.x & 63;
    int wid  = threadIdx.x >> 6;
    if (lane == 0) red[wid] = local;
    __syncthreads();
    if (threadIdx.x == 0) {
        float s = red[0] + red[1] + red[2] + red[3];
        atomicAdd(&sums[p], s);
    }
}

__global__ void finalize_kernel(const float* __restrict__ sums, float* __restrict__ out) {
    if (threadIdx.x == 0 && blockIdx.x == 0) {
        float cnt = 0.0f, vals = 0.0f;
#pragma unroll
        for (int p = 0; p < kP; ++p) {
            float pen = sums[p];
            float keep = (pen < THRESH_F) ? 1.0f : 0.0f;
            cnt += keep;
            float s = 1.0f / (1.0f + expf(-pen / THRESH_F));
            vals += (s - 0.5f) * keep;
        }
        float loss = (cnt > 0.0f) ? (vals / fmaxf(cnt, 1.0f)) : 0.0f;
        out[0] = loss * WEIGHT_F;
    }
}
// ----------------------------------------------------------------------

extern "C" void kernel_launch(void* const* d_in, const int* in_sizes, int n_in,
                              void* d_out, int out_size, void* d_ws, size_t ws_size,
                              hipStream_t stream) {
    const float* verts = (const float*)d_in[0];
    const float* trans = (const float*)d_in[1];
    const int*   faces = (const int*)d_in[2];
    const int*   coll  = (const int*)d_in[3];
    float* out  = (float*)d_out;

    float*    sums    = (float*)d_ws;
    unsigned* counter = (unsigned*)((char*)d_ws + 64);
    const size_t cones_off   = 256;
    const size_t cones_bytes = (size_t)kP * kTF * 8 * sizeof(float);    // 7.05 MB
    const size_t tv_off      = cones_off + cones_bytes;
    const size_t tv_bytes    = (size_t)kP * kTF * 16 * sizeof(float);   // 14.1 MB

    if (ws_size >= tv_off + tv_bytes) {
        float* cones = (float*)((char*)d_ws + cones_off);
        float* tv    = (float*)((char*)d_ws + tv_off);
        build_kernel<<<kBuildBlocks, 256, 0, stream>>>(verts, trans, faces,
                                                       cones, tv, sums, counter);
        pen_kernel<<<kPenBlocks, 256, 0, stream>>>(coll, cones, tv, sums, counter, out);
    } else {
        init_sums_kernel<<<1, 64, 0, stream>>>(sums);
        dim3 grid_main(kC / 256, kP);
        pen_kernel_direct<<<grid_main, 256, 0, stream>>>(coll, verts, trans, faces, sums);
        finalize_kernel<<<1, 64, 0, stream>>>(sums, out);
    }
}

// Round 4
// 109.221 us; speedup vs baseline: 1.2161x; 1.2161x over previous
//
#include <hip/hip_runtime.h>
#include <math.h>

namespace {
constexpr int kB  = 16;
constexpr int kNV = 6890;
constexpr int kNF = 13776;
constexpr int kTF = 2 * kNF;              // 27552 triangles per person-pair
constexpr int kP  = kB / 2;               // 8 pairs
constexpr int kC  = 65536;
constexpr int kBuildChunks = (kTF + 255) / 256;      // 108
constexpr int kBuildBlocks = kP * kBuildChunks;      // 864
}
#define SIGMA_F 1e-4f
#define EPS_F   1e-9f
#define THRESH_F 2000.0f
#define WEIGHT_F 0.1f

// ws layout: [0..31] sums[8] floats; [256..] rec: per triangle 16 floats / 64 B:
//   r[0..3]   v0.x v0.y v0.z v1.x
//   r[4..7]   v1.y v1.z v2.x v2.y
//   r[8..11]  v2.z  cx   cy   cz
//   r[12..15] nx    ny   nz  inv_rad
// Intruder side reads f4[0..2] (one 64-B line); receiver side reads f4[2..3]
// (same single line). One scattered line per side per collision.

// Kernel A: translate vertices, precompute cone frame, pack record; zero sums.
// blk&7 = pair -> same XCD as pen's readers (round-robin block->XCD dispatch),
// so pair p's 1.76 MB of records is written into (and read from) XCD p's L2.
__global__ void __launch_bounds__(256)
build_kernel(const float* __restrict__ verts,
             const float* __restrict__ trans,
             const int*   __restrict__ faces,
             float* __restrict__ rec,
             float* __restrict__ sums) {
    if (blockIdx.x == 0 && threadIdx.x < kP) sums[threadIdx.x] = 0.0f;
    int blk = blockIdx.x;
    int p = blk & 7;
    int t = (blk >> 3) * 256 + threadIdx.x;
    if (t >= kTF) return;
    int half = (t >= kNF) ? 1 : 0;
    int b = 2 * p + half;
    int f = t - half * kNF;
    float tx = trans[3 * b + 0];
    float ty = trans[3 * b + 1];
    float tz = trans[3 * b + 2];
    float3 v[3];
#pragma unroll
    for (int k = 0; k < 3; ++k) {
        int vi = faces[3 * f + k];
        const float* vp = verts + ((size_t)b * kNV + vi) * 3;
        v[k] = make_float3(vp[0] + tx, vp[1] + ty, vp[2] + tz);
    }
    // receiver cone frame (reference order of ops)
    float e1x = v[1].x - v[0].x, e1y = v[1].y - v[0].y, e1z = v[1].z - v[0].z;
    float e2x = v[2].x - v[0].x, e2y = v[2].y - v[0].y, e2z = v[2].z - v[0].z;
    float nx = e1y * e2z - e1z * e2y;
    float ny = e1z * e2x - e1x * e2z;
    float nz = e1x * e2y - e1y * e2x;
    float nn = sqrtf(nx * nx + ny * ny + nz * nz) + EPS_F;
    nx /= nn; ny /= nn; nz /= nn;
    float cx = (v[0].x + v[1].x + v[2].x) / 3.0f;
    float cy = (v[0].y + v[1].y + v[2].y) / 3.0f;
    float cz = (v[0].z + v[1].z + v[2].z) / 3.0f;
    float r2 = 0.0f;
#pragma unroll
    for (int k = 0; k < 3; ++k) {
        float dx = v[k].x - cx, dy = v[k].y - cy, dz = v[k].z - cz;
        r2 = fmaxf(r2, dx * dx + dy * dy + dz * dz);
    }
    float inv_rad = 1.0f / (sqrtf(r2) + EPS_F);
    int g = p * kTF + t;
    float4* dst = (float4*)(rec + (size_t)g * 16);
    float4 a0; a0.x = v[0].x; a0.y = v[0].y; a0.z = v[0].z; a0.w = v[1].x;
    float4 a1; a1.x = v[1].y; a1.y = v[1].z; a1.z = v[2].x; a1.w = v[2].y;
    float4 a2; a2.x = v[2].z; a2.y = cx;     a2.z = cy;     a2.w = cz;
    float4 a3; a3.x = nx;     a3.y = ny;     a3.z = nz;     a3.w = inv_rad;
    dst[0] = a0; dst[1] = a1; dst[2] = a2; dst[3] = a3;
}

// Kernel B: one thread per collision; wave+block reduce; 1 atomic per block.
// No fences anywhere in the hot path.
__global__ void __launch_bounds__(256)
pen_kernel(const int* __restrict__ coll,
           const float* __restrict__ rec,
           float* __restrict__ sums) {
    int blk = blockIdx.x;
    int p = blk & 7;                         // XCD-pinned pair
    int i = (blk >> 3) * 256 + threadIdx.x;  // [0, 65536) exactly
    int2 idx = ((const int2*)coll)[p * kC + i];
    float local = 0.0f;
    if (idx.x != idx.y) {
        int rbase = p * kTF;
        const float4* rb = (const float4*)rec + (size_t)(rbase + idx.y) * 4;
        const float4* ib = (const float4*)rec + (size_t)(rbase + idx.x) * 4;
        float4 r2q = rb[2];                  // v2.z, cx, cy, cz
        float4 r3q = rb[3];                  // nx, ny, nz, inv_rad
        float4 w0 = ib[0];                   // v0.xyz, v1.x
        float4 w1 = ib[1];                   // v1.yz, v2.xy
        float4 w2 = ib[2];                   // v2.z, (c..)
        float cx = r2q.y, cy = r2q.z, cz = r2q.w;
        float nx = r3q.x, ny = r3q.y, nz = r3q.z, inv_rad = r3q.w;
        float ivx[3] = {w0.x, w0.w, w1.z};
        float ivy[3] = {w0.y, w1.x, w1.w};
        float ivz[3] = {w0.z, w1.y, w2.x};
        float acc = 0.0f;
#pragma unroll
        for (int k = 0; k < 3; ++k) {
            float dx = ivx[k] - cx, dy = ivy[k] - cy, dz = ivz[k] - cz;
            float d = dx * nx + dy * ny + dz * nz;
            float px = dx - d * nx, py = dy - d * ny, pz = dz - d * nz;
            float radial = sqrtf(px * px + py * py + pz * pz);
            float fa = fmaxf(-d / SIGMA_F, 0.0f);
            float fb = fmaxf(1.0f - radial * inv_rad, 0.0f);
            float fd = fa * fb;
            acc += fd * fd;
        }
        local = acc;
    }
#pragma unroll
    for (int off = 32; off > 0; off >>= 1)
        local += __shfl_down(local, off, 64);
    __shared__ float red[4];
    int lane = threadIdx.x & 63;
    int wid  = threadIdx.x >> 6;
    if (lane == 0) red[wid] = local;
    __syncthreads();
    if (threadIdx.x == 0) {
        float s = red[0] + red[1] + red[2] + red[3];
        atomicAdd(&sums[p], s);
    }
}

__global__ void finalize_kernel(const float* __restrict__ sums, float* __restrict__ out) {
    if (threadIdx.x == 0 && blockIdx.x == 0) {
        float cnt = 0.0f, vals = 0.0f;
#pragma unroll
        for (int p = 0; p < kP; ++p) {
            float pen = sums[p];
            float keep = (pen < THRESH_F) ? 1.0f : 0.0f;
            cnt += keep;
            float s = 1.0f / (1.0f + expf(-pen / THRESH_F));
            vals += (s - 0.5f) * keep;
        }
        float loss = (cnt > 0.0f) ? (vals / fmaxf(cnt, 1.0f)) : 0.0f;
        out[0] = loss * WEIGHT_F;
    }
}

// ---------- fallback path (ws too small; not expected to run) ----------
__global__ void init_sums_kernel(float* __restrict__ sums) {
    int t = threadIdx.x;
    if (t < kP) sums[t] = 0.0f;
}

__global__ void __launch_bounds__(256)
pen_kernel_direct(const int* __restrict__ coll,
                  const float* __restrict__ verts,
                  const float* __restrict__ trans,
                  const int* __restrict__ faces,
                  float* __restrict__ sums) {
    int p = blockIdx.y;
    int i = blockIdx.x * blockDim.x + threadIdx.x;
    float local = 0.0f;
    if (i < kC) {
        int2 idx = ((const int2*)coll)[(size_t)p * kC + i];
        if (idx.x != idx.y) {
            float3 rv[3], iv[3];
#pragma unroll
            for (int s = 0; s < 2; ++s) {
                int t = s ? idx.x : idx.y;
                int half = (t >= kNF) ? 1 : 0;
                int b = 2 * p + half;
                int f = t - half * kNF;
                float tx = trans[3 * b + 0], ty = trans[3 * b + 1], tz = trans[3 * b + 2];
#pragma unroll
                for (int k = 0; k < 3; ++k) {
                    int vi = faces[3 * f + k];
                    const float* vp = verts + ((size_t)b * kNV + vi) * 3;
                    float3 vv = make_float3(vp[0] + tx, vp[1] + ty, vp[2] + tz);
                    if (s) iv[k] = vv; else rv[k] = vv;
                }
            }
            float e1x = rv[1].x - rv[0].x, e1y = rv[1].y - rv[0].y, e1z = rv[1].z - rv[0].z;
            float e2x = rv[2].x - rv[0].x, e2y = rv[2].y - rv[0].y, e2z = rv[2].z - rv[0].z;
            float nx = e1y * e2z - e1z * e2y;
            float ny = e1z * e2x - e1x * e2z;
            float nz = e1x * e2y - e1y * e2x;
            float nn = sqrtf(nx * nx + ny * ny + nz * nz) + EPS_F;
            nx /= nn; ny /= nn; nz /= nn;
            float cx = (rv[0].x + rv[1].x + rv[2].x) / 3.0f;
            float cy = (rv[0].y + rv[1].y + rv[2].y) / 3.0f;
            float cz = (rv[0].z + rv[1].z + rv[2].z) / 3.0f;
            float r2 = 0.0f;
#pragma unroll
            for (int k = 0; k < 3; ++k) {
                float dx = rv[k].x - cx, dy = rv[k].y - cy, dz = rv[k].z - cz;
                r2 = fmaxf(r2, dx * dx + dy * dy + dz * dz);
            }
            float inv_rad = sqrtf(r2) + EPS_F;
            float acc = 0.0f;
#pragma unroll
            for (int k = 0; k < 3; ++k) {
                float dx = iv[k].x - cx, dy = iv[k].y - cy, dz = iv[k].z - cz;
                float d = dx * nx + dy * ny + dz * nz;
                float px = dx - d * nx, py = dy - d * ny, pz = dz - d * nz;
                float radial = sqrtf(px * px + py * py + pz * pz);
                float fa = fmaxf(-d / SIGMA_F, 0.0f);
                float fb = fmaxf(1.0f - radial / inv_rad, 0.0f);
                float fd = fa * fb;
                acc += fd * fd;
            }
            local = acc;
        }
    }
#pragma unroll
    for (int off = 32; off > 0; off >>= 1)
        local += __shfl_down(local, off, 64);
    __shared__ float red[4];
    int lane = threadIdx.x & 63;
    int wid  = threadIdx.x >> 6;
    if (lane == 0) red[wid] = local;
    __syncthreads();
    if (threadIdx.x == 0) {
        float s = red[0] + red[1] + red[2] + red[3];
        atomicAdd(&sums[p], s);
    }
}
// ----------------------------------------------------------------------

extern "C" void kernel_launch(void* const* d_in, const int* in_sizes, int n_in,
                              void* d_out, int out_size, void* d_ws, size_t ws_size,
                              hipStream_t stream) {
    const float* verts = (const float*)d_in[0];
    const float* trans = (const float*)d_in[1];
    const int*   faces = (const int*)d_in[2];
    const int*   coll  = (const int*)d_in[3];
    float* out  = (float*)d_out;

    float* sums = (float*)d_ws;
    const size_t rec_off   = 256;
    const size_t rec_bytes = (size_t)kP * kTF * 16 * sizeof(float);   // 14.1 MB

    if (ws_size >= rec_off + rec_bytes) {
        float* rec = (float*)((char*)d_ws + rec_off);
        build_kernel<<<kBuildBlocks, 256, 0, stream>>>(verts, trans, faces, rec, sums);
        pen_kernel<<<kP * (kC / 256), 256, 0, stream>>>(coll, rec, sums);
        finalize_kernel<<<1, 64, 0, stream>>>(sums, out);
    } else {
        init_sums_kernel<<<1, 64, 0, stream>>>(sums);
        dim3 grid_main(kC / 256, kP);
        pen_kernel_direct<<<grid_main, 256, 0, stream>>>(coll, verts, trans, faces, sums);
        finalize_kernel<<<1, 64, 0, stream>>>(sums, out);
    }
}

// Round 5
// 81.852 us; speedup vs baseline: 1.6227x; 1.3344x over previous
//
#include <hip/hip_runtime.h>
#include <math.h>

namespace {
constexpr int kB  = 16;
constexpr int kNV = 6890;
constexpr int kNF = 13776;
constexpr int kP  = kB / 2;               // 8 person-pairs
constexpr int kC  = 65536;
constexpr int kChunks    = kC / 256;      // 256 blocks per pair
constexpr int kPenBlocks = kP * kChunks;  // 2048
}
#define SIGMA_F 1e-4f
#define EPS_F   1e-9f
#define THRESH_F 2000.0f
#define WEIGHT_F 0.1f

// Fully fused: no intermediate triangle buffer (L2 is invalidated between
// kernels, so a staging buffer is always re-fetched from L3 — measured R3:
// pen FETCH 12.35 MB of a 14.1 MB rec array). Direct gather keeps the hot
// set at verts(1.3 MB)+faces(165 KB), L2-resident after first touch.
// One partial per block -> no atomics, no zero-init kernel.
__global__ void __launch_bounds__(256)
pen_direct(const int* __restrict__ coll,
           const float* __restrict__ verts,
           const float* __restrict__ trans,
           const int* __restrict__ faces,
           float* __restrict__ partials) {
    int blk = blockIdx.x;
    int p = blk & 7;                         // uniform per block (SGPR)
    int i = (blk >> 3) * 256 + threadIdx.x;  // [0, kC)
    int2 idx = ((const int2*)coll)[p * kC + i];

    // per-pair translations (uniform -> scalar loads)
    const float t0x = trans[6 * p + 0], t0y = trans[6 * p + 1], t0z = trans[6 * p + 2];
    const float t1x = trans[6 * p + 3], t1y = trans[6 * p + 4], t1z = trans[6 * p + 5];

    float local = 0.0f;
    if (idx.x != idx.y) {
        // face rows for intruder (idx.x) and receiver (idx.y) — independent loads
        int hi = (idx.x >= kNF) ? 1 : 0;
        int hr = (idx.y >= kNF) ? 1 : 0;
        const int* fi = faces + 3 * (idx.x - hi * kNF);
        const int* fr = faces + 3 * (idx.y - hr * kNF);
        int vi0 = fi[0], vi1 = fi[1], vi2 = fi[2];
        int vr0 = fr[0], vr1 = fr[1], vr2 = fr[2];

        size_t bi = (size_t)(2 * p + hi) * kNV;
        size_t br = (size_t)(2 * p + hr) * kNV;
        float tix = hi ? t1x : t0x, tiy = hi ? t1y : t0y, tiz = hi ? t1z : t0z;
        float trx = hr ? t1x : t0x, try_ = hr ? t1y : t0y, trz = hr ? t1z : t0z;

        // 6 independent 12-B vertex gathers
        const float* q;
        q = verts + (bi + vi0) * 3; float3 i0 = make_float3(q[0] + tix, q[1] + tiy, q[2] + tiz);
        q = verts + (bi + vi1) * 3; float3 i1 = make_float3(q[0] + tix, q[1] + tiy, q[2] + tiz);
        q = verts + (bi + vi2) * 3; float3 i2 = make_float3(q[0] + tix, q[1] + tiy, q[2] + tiz);
        q = verts + (br + vr0) * 3; float3 r0 = make_float3(q[0] + trx, q[1] + try_, q[2] + trz);
        q = verts + (br + vr1) * 3; float3 r1 = make_float3(q[0] + trx, q[1] + try_, q[2] + trz);
        q = verts + (br + vr2) * 3; float3 r2 = make_float3(q[0] + trx, q[1] + try_, q[2] + trz);

        // receiver cone frame (reference order of ops)
        float e1x = r1.x - r0.x, e1y = r1.y - r0.y, e1z = r1.z - r0.z;
        float e2x = r2.x - r0.x, e2y = r2.y - r0.y, e2z = r2.z - r0.z;
        float nx = e1y * e2z - e1z * e2y;
        float ny = e1z * e2x - e1x * e2z;
        float nz = e1x * e2y - e1y * e2x;
        float nn = sqrtf(nx * nx + ny * ny + nz * nz) + EPS_F;
        nx /= nn; ny /= nn; nz /= nn;
        float cx = (r0.x + r1.x + r2.x) / 3.0f;
        float cy = (r0.y + r1.y + r2.y) / 3.0f;
        float cz = (r0.z + r1.z + r2.z) / 3.0f;
        float r2m = 0.0f;
        {
            float dx = r0.x - cx, dy = r0.y - cy, dz = r0.z - cz;
            r2m = fmaxf(r2m, dx * dx + dy * dy + dz * dz);
            dx = r1.x - cx; dy = r1.y - cy; dz = r1.z - cz;
            r2m = fmaxf(r2m, dx * dx + dy * dy + dz * dz);
            dx = r2.x - cx; dy = r2.y - cy; dz = r2.z - cz;
            r2m = fmaxf(r2m, dx * dx + dy * dy + dz * dz);
        }
        float rad_eps = sqrtf(r2m) + EPS_F;

        float3 iv[3] = {i0, i1, i2};
        float acc = 0.0f;
#pragma unroll
        for (int k = 0; k < 3; ++k) {
            float dx = iv[k].x - cx, dy = iv[k].y - cy, dz = iv[k].z - cz;
            float d = dx * nx + dy * ny + dz * nz;
            float px = dx - d * nx, py = dy - d * ny, pz = dz - d * nz;
            float radial = sqrtf(px * px + py * py + pz * pz);
            float fa = fmaxf(-d / SIGMA_F, 0.0f);
            float fb = fmaxf(1.0f - radial / rad_eps, 0.0f);
            float fd = fa * fb;
            acc += fd * fd;
        }
        local = acc;
    }

    // wave(64) reduce -> block reduce -> one partial per block (no atomics)
#pragma unroll
    for (int off = 32; off > 0; off >>= 1)
        local += __shfl_down(local, off, 64);
    __shared__ float red[4];
    int lane = threadIdx.x & 63;
    int wid  = threadIdx.x >> 6;
    if (lane == 0) red[wid] = local;
    __syncthreads();
    if (threadIdx.x == 0)
        partials[blk] = red[0] + red[1] + red[2] + red[3];
}

// 1 block, 512 threads = 8 waves; wave w reduces pair w's 256 partials
// (blocks with blk&7 == w), then thread 0 applies the threshold/sigmoid.
__global__ void __launch_bounds__(512)
finalize_kernel(const float* __restrict__ partials, float* __restrict__ out) {
    int wv = threadIdx.x >> 6;    // pair
    int lane = threadIdx.x & 63;
    float s = 0.0f;
#pragma unroll
    for (int k = 0; k < 4; ++k) {
        int j = lane + 64 * k;               // chunk index [0,256)
        s += partials[wv + 8 * j];
    }
#pragma unroll
    for (int off = 32; off > 0; off >>= 1)
        s += __shfl_down(s, off, 64);
    __shared__ float pen[kP];
    if (lane == 0) pen[wv] = s;
    __syncthreads();
    if (threadIdx.x == 0) {
        float cnt = 0.0f, vals = 0.0f;
#pragma unroll
        for (int q = 0; q < kP; ++q) {
            float pq = pen[q];
            float keep = (pq < THRESH_F) ? 1.0f : 0.0f;
            cnt += keep;
            float sg = 1.0f / (1.0f + expf(-pq / THRESH_F));
            vals += (sg - 0.5f) * keep;
        }
        float loss = (cnt > 0.0f) ? (vals / fmaxf(cnt, 1.0f)) : 0.0f;
        out[0] = loss * WEIGHT_F;
    }
}

extern "C" void kernel_launch(void* const* d_in, const int* in_sizes, int n_in,
                              void* d_out, int out_size, void* d_ws, size_t ws_size,
                              hipStream_t stream) {
    const float* verts = (const float*)d_in[0];
    const float* trans = (const float*)d_in[1];
    const int*   faces = (const int*)d_in[2];
    const int*   coll  = (const int*)d_in[3];
    float* out      = (float*)d_out;
    float* partials = (float*)d_ws;          // kPenBlocks floats (8 KB)

    pen_direct<<<kPenBlocks, 256, 0, stream>>>(coll, verts, trans, faces, partials);
    finalize_kernel<<<1, 512, 0, stream>>>(partials, out);
}